// Round 2
// baseline (369.810 us; speedup 1.0000x reference)
//
#include <hip/hip_runtime.h>
#include <math.h>

#define N_B   16
#define C_IN  256
#define MIP   64
#define HW    96
#define PTOT  192   // 2*HW
#define KK    7

typedef float floatx4 __attribute__((ext_vector_type(4)));

// ---------------------------------------------------------------------------
// Kernel A: per-(n,c) plane -> row means and col means
// pooled[(n*256 + c)*192 + p]; p<96: row-mean[p], p>=96: col-mean[p-96]
// ---------------------------------------------------------------------------
__global__ void pool_kernel(const float* __restrict__ x, float* __restrict__ pooled) {
    int plane = blockIdx.x;                       // n*256 + c
    const float* xp = x + (size_t)plane * (HW * HW);
    __shared__ float sm[HW * 97];                 // padded stride 97
    int t = threadIdx.x;
    #pragma unroll
    for (int k = 0; k < 9; ++k) {
        int idx = t + k * 256;                    // float4 index
        floatx4 v = ((const floatx4*)xp)[idx];
        int flat = idx * 4;
        int row = flat / HW;
        int col = flat - row * HW;
        float* d = &sm[row * 97 + col];
        d[0] = v.x; d[1] = v.y; d[2] = v.z; d[3] = v.w;
    }
    __syncthreads();
    float* pp = pooled + (size_t)plane * PTOT;
    if (t < HW) {
        float rs = 0.f;
        #pragma unroll 4
        for (int j = 0; j < HW; ++j) rs += sm[t * 97 + j];
        pp[t] = rs * (1.f / 96.f);
    } else if (t < 2 * HW) {
        int c = t - HW;
        float cs = 0.f;
        #pragma unroll 4
        for (int i = 0; i < HW; ++i) cs += sm[i * 97 + c];
        pp[HW + c] = cs * (1.f / 96.f);
    }
}

// ---------------------------------------------------------------------------
// Kernel B1: conv1x1 256->64 over ALL (n, p) positions, one thread per output.
// grid (48, 16) x 256 thr = 768 blocks = 12 waves/CU -> latency hidden.
// y0g[(n*192 + p)*64 + o] = bias + sum_c w[o][c] * pooled[n][c][p]
// Weights read row-major as float4 (64 KB, L1/L2-hot, identical for every
// block); pooled reads are wave-uniform broadcasts (same p across a wave).
// ---------------------------------------------------------------------------
__global__ __launch_bounds__(256) void conv_kernel(
    const float* __restrict__ pooled,
    const float* __restrict__ w_c1, const float* __restrict__ b_c1,
    float* __restrict__ y0g)
{
    int t = threadIdx.x;
    int o  = t & 63;
    int pl = t >> 6;                       // 0..3
    int p  = blockIdx.x * 4 + pl;          // 0..191
    int n  = blockIdx.y;
    const float* pr = pooled + (size_t)n * C_IN * PTOT + p;   // stride PTOT over c
    const floatx4* wr = (const floatx4*)(w_c1 + o * C_IN);
    float acc = 0.f;
    #pragma unroll 8
    for (int c4 = 0; c4 < C_IN / 4; ++c4) {
        floatx4 w4 = wr[c4];
        int c = c4 * 4;
        acc += w4.x * pr[(c + 0) * PTOT];
        acc += w4.y * pr[(c + 1) * PTOT];
        acc += w4.z * pr[(c + 2) * PTOT];
        acc += w4.w * pr[(c + 3) * PTOT];
    }
    y0g[((size_t)n * PTOT + p) * 64 + o] = acc + b_c1[o];
}

// ---------------------------------------------------------------------------
// Kernel B2: mid pipeline (involution1 + BN + hswish + involution2) on a
// tile of 8 positions. grid (24,16) = 384 blocks. Halo: lz tile [p0,p0+8)
// needs yt at [p0-3,p0+11) (14 pos) which needs y0 at [p0-6,p0+14) (20 pos).
// Tiles never straddle the 96 boundary (96 = 12*8) -> side uniform per block.
// Writes lz to global (L2-resident, 786 KB).
// ---------------------------------------------------------------------------
__global__ __launch_bounds__(256) void mid_kernel(
    const float* __restrict__ y0g,
    const float* __restrict__ i1_w1, const float* __restrict__ i1_b1,
    const float* __restrict__ i1_w2, const float* __restrict__ i1_b2,
    const float* __restrict__ bn_g, const float* __restrict__ bn_b,
    const float* __restrict__ bn_m, const float* __restrict__ bn_v,
    const float* __restrict__ h_w1, const float* __restrict__ h_b1,
    const float* __restrict__ h_w2, const float* __restrict__ h_b2,
    const float* __restrict__ v_w1, const float* __restrict__ v_b1,
    const float* __restrict__ v_w2, const float* __restrict__ v_b2,
    float* __restrict__ lzg)
{
    int p0 = blockIdx.x * 8;       // 0..184
    int n  = blockIdx.y;
    int t  = threadIdx.x;
    int side = (p0 >= HW) ? 1 : 0; // uniform per block
    int lo = side * HW;

    __shared__ float y0t[20 * 64];   // y0 at [p0-6, p0+14), zero outside [0,192)
    __shared__ float yt[14 * 64];    // mid1 output at [p0-3, p0+11)
    __shared__ float lt[14 * 16];
    __shared__ float lwgt[14 * 28];
    __shared__ float lt2[8 * 16];
    __shared__ float lwgt2[8 * 28];

    // ---- stage y0 neighborhood ----
    #pragma unroll
    for (int i = 0; i < 5; ++i) {
        int flat = t + 256 * i;            // 1280 = 20*64
        int j = flat >> 6, o = flat & 63;
        int r = p0 - 6 + j;
        y0t[flat] = (r >= 0 && r < PTOT) ? y0g[((size_t)n * PTOT + r) * 64 + o] : 0.f;
    }
    __syncthreads();

    // ---- mid1: lt = w1 . y0(center), 14 pos x 16 ----
    if (t < 224) {
        int q = t >> 4, i = t & 15;
        float a = i1_b1[i];
        const float* wr = i1_w1 + i * MIP;
        #pragma unroll 8
        for (int oo = 0; oo < MIP; ++oo) a += wr[oo] * y0t[(q + 3) * 64 + oo];
        lt[t] = a;
    }
    __syncthreads();
    // ---- mid1: lwgt (only taps ky*7+3 survive on the (192,1) map) ----
    for (int idx = t; idx < 392; idx += 256) {   // 14*28
        int q = idx / 28, m = idx - q * 28;
        int g = m / 7, ky = m - g * 7;
        int wq = g * 49 + ky * 7 + 3;
        float a = i1_b2[wq];
        const float* wr = i1_w2 + wq * 16;
        #pragma unroll
        for (int r = 0; r < 16; ++r) a += wr[r] * lt[q * 16 + r];
        lwgt[idx] = a;
    }
    __syncthreads();
    // ---- mid1: involution + BN + hswish -> yt, 14 pos x 64 ch ----
    for (int idx = t; idx < 896; idx += 256) {
        int q = idx >> 6, ch = idx & 63;
        int g = ch >> 4;
        float a = 0.f;
        #pragma unroll
        for (int ky = 0; ky < KK; ++ky)
            a += lwgt[q * 28 + g * 7 + ky] * y0t[(q + ky) * 64 + ch];
        float inv_std = rsqrtf(bn_v[ch] + 1e-5f);
        float v = (a - bn_m[ch]) * (bn_g[ch] * inv_std) + bn_b[ch];
        yt[idx] = v * fminf(fmaxf(v + 3.f, 0.f), 6.f) * (1.f / 6.f);
    }
    __syncthreads();

    // ---- mid2 (branch weights uniform per block) ----
    const float* ww1 = side ? v_w1 : h_w1;
    const float* bb1 = side ? v_b1 : h_b1;
    const float* ww2 = side ? v_w2 : h_w2;
    const float* bb2 = side ? v_b2 : h_b2;

    // lt2: 8 pos x 16 (center p0+pp is always inside the half)
    if (t < 128) {
        int pp = t >> 4, i = t & 15;
        float a = bb1[i];
        const float* wr = ww1 + i * MIP;
        #pragma unroll 8
        for (int oo = 0; oo < MIP; ++oo) a += wr[oo] * yt[(pp + 3) * 64 + oo];
        lt2[t] = a;
    }
    __syncthreads();
    // lwgt2: H side taps ky*7+3, W side taps 21+kx
    if (t < 224) {     // 8*28
        int pp = t / 28, m = t - pp * 28;
        int g = m / 7, kk = m - g * 7;
        int wq = side ? (g * 49 + 21 + kk) : (g * 49 + kk * 7 + 3);
        float a = bb2[wq];
        const float* wr = ww2 + wq * 16;
        #pragma unroll
        for (int r = 0; r < 16; ++r) a += wr[r] * lt2[pp * 16 + r];
        lwgt2[t] = a;
    }
    __syncthreads();
    // lz: involution over the half (zero outside [lo, lo+96)) -> global
    for (int idx = t; idx < 512; idx += 256) {
        int pp = idx >> 6, ch = idx & 63;
        int g = ch >> 4;
        float a = 0.f;
        #pragma unroll
        for (int k = 0; k < KK; ++k) {
            int pos = p0 + pp + k - 3;
            float v = (pos >= lo && pos < lo + HW) ? yt[(pp + k) * 64 + ch] : 0.f;
            a += lwgt2[pp * 28 + g * 7 + k] * v;
        }
        lzg[((size_t)n * PTOT + p0 + pp) * 64 + ch] = a;
    }
}

// ---------------------------------------------------------------------------
// Kernel B3: final conv 64->256 + sigmoid, one thread per output.
// grid (64, 16, 2) x 384 thr = 2048 blocks, 12K waves. lz half staged into
// LDS with stride-65 padding -> conflict-free (bank = (p+ch)%32).
// Coalesced stores (lanes traverse p).
// ---------------------------------------------------------------------------
__global__ __launch_bounds__(384) void final_kernel(
    const float* __restrict__ lzg,
    const float* __restrict__ w_h, const float* __restrict__ b_h,
    const float* __restrict__ w_w, const float* __restrict__ b_w,
    float* __restrict__ a_h, float* __restrict__ a_w)
{
    int side = blockIdx.z;
    int n    = blockIdx.y;
    int co0  = blockIdx.x * 4;
    int t    = threadIdx.x;
    int lo   = side * HW;
    __shared__ float lzs[HW * 65];   // padded
    const float* src = lzg + ((size_t)n * PTOT + lo) * 64;
    for (int flat = t; flat < HW * 64; flat += 384) {
        int pp = flat >> 6, ch = flat & 63;
        lzs[pp * 65 + ch] = src[flat];
    }
    __syncthreads();
    int p_l  = t % HW;          // 0..95
    int co_l = t / HW;          // 0..3
    int co   = co0 + co_l;
    const float* wr = (side ? w_w : w_h) + co * MIP;
    float acc = (side ? b_w : b_h)[co];
    #pragma unroll 8
    for (int ch = 0; ch < MIP; ++ch) acc += wr[ch] * lzs[p_l * 65 + ch];
    float* dst = side ? a_w : a_h;
    dst[((size_t)n * C_IN + co) * HW + p_l] = 1.f / (1.f + __expf(-acc));
}

// ---------------------------------------------------------------------------
// Kernel C: out = x * a_w[j] * a_h[i], per-plane, float4, NT stores
// ---------------------------------------------------------------------------
__global__ void apply_kernel(const float* __restrict__ x,
                             const float* __restrict__ a_h, const float* __restrict__ a_w,
                             float* __restrict__ out) {
    int plane = blockIdx.x;   // n*256 + c
    const floatx4* xp = (const floatx4*)(x + (size_t)plane * (HW * HW));
    floatx4* op = (floatx4*)(out + (size_t)plane * (HW * HW));
    __shared__ float sah[HW];
    __shared__ float saw[HW];
    int t = threadIdx.x;
    if (t < HW) {
        sah[t] = a_h[(size_t)plane * HW + t];
        saw[t] = a_w[(size_t)plane * HW + t];
    }
    __syncthreads();
    #pragma unroll
    for (int k = 0; k < 9; ++k) {
        int idx = t + k * 256;          // float4 index, 2304 per plane
        floatx4 v = xp[idx];
        int row = idx / 24;
        int c4 = (idx - row * 24) * 4;
        float ah = sah[row];
        v.x *= ah * saw[c4 + 0];
        v.y *= ah * saw[c4 + 1];
        v.z *= ah * saw[c4 + 2];
        v.w *= ah * saw[c4 + 3];
        __builtin_nontemporal_store(v, &op[idx]);
    }
}

extern "C" void kernel_launch(void* const* d_in, const int* in_sizes, int n_in,
                              void* d_out, int out_size, void* d_ws, size_t ws_size,
                              hipStream_t stream) {
    const float* x      = (const float*)d_in[0];
    const float* w_c1   = (const float*)d_in[1];
    const float* b_c1   = (const float*)d_in[2];
    const float* i1_w1  = (const float*)d_in[3];
    const float* i1_b1  = (const float*)d_in[4];
    const float* i1_w2  = (const float*)d_in[5];
    const float* i1_b2  = (const float*)d_in[6];
    const float* bn_g   = (const float*)d_in[7];
    const float* bn_b   = (const float*)d_in[8];
    const float* bn_m   = (const float*)d_in[9];
    const float* bn_v   = (const float*)d_in[10];
    const float* ih_w1  = (const float*)d_in[11];
    const float* ih_b1  = (const float*)d_in[12];
    const float* ih_w2  = (const float*)d_in[13];
    const float* ih_b2  = (const float*)d_in[14];
    const float* w_h    = (const float*)d_in[15];
    const float* b_h    = (const float*)d_in[16];
    const float* iw_w1  = (const float*)d_in[17];
    const float* iw_b1  = (const float*)d_in[18];
    const float* iw_w2  = (const float*)d_in[19];
    const float* iw_b2  = (const float*)d_in[20];
    const float* w_w    = (const float*)d_in[21];
    const float* b_w    = (const float*)d_in[22];
    float* out = (float*)d_out;

    // Workspace layout: EXACTLY the previously-verified 1,572,864-float
    // footprint (6.29 MB). New temporaries alias dead regions:
    //   lzg aliases pooled  (pooled dead after conv_kernel; mid writes lzg after)
    //   y0g aliases a_h     (y0g dead after mid_kernel; final writes a_h after)
    float* ws = (float*)d_ws;
    float* pooled = ws;                       // 786432 floats
    float* a_h    = pooled + 786432;          // 393216
    float* a_w    = a_h + 393216;             // 393216
    float* lzg    = pooled;                   // 196608 (aliases pooled)
    float* y0g    = a_h;                      // 196608 (aliases a_h)

    pool_kernel<<<dim3(N_B * C_IN), dim3(256), 0, stream>>>(x, pooled);
    conv_kernel<<<dim3(48, N_B), dim3(256), 0, stream>>>(pooled, w_c1, b_c1, y0g);
    mid_kernel<<<dim3(24, N_B), dim3(256), 0, stream>>>(
        y0g, i1_w1, i1_b1, i1_w2, i1_b2,
        bn_g, bn_b, bn_m, bn_v,
        ih_w1, ih_b1, ih_w2, ih_b2,
        iw_w1, iw_b1, iw_w2, iw_b2, lzg);
    final_kernel<<<dim3(64, N_B, 2), dim3(384), 0, stream>>>(
        lzg, w_h, b_h, w_w, b_w, a_h, a_w);
    apply_kernel<<<dim3(N_B * C_IN), dim3(256), 0, stream>>>(x, a_h, a_w, out);
}

// Round 3
// 349.353 us; speedup vs baseline: 1.0586x; 1.0586x over previous
//
#include <hip/hip_runtime.h>
#include <math.h>

#define N_B   16
#define C_IN  256
#define MIP   64
#define HW    96
#define PTOT  192   // 2*HW
#define KK    7

typedef float floatx4 __attribute__((ext_vector_type(4)));

// ---------------------------------------------------------------------------
// Kernel A: per-(n,c) plane -> row means and col means
// pooled[(n*256 + c)*192 + p]; p<96: row-mean[p], p>=96: col-mean[p-96]
// (verified, unchanged)
// ---------------------------------------------------------------------------
__global__ void pool_kernel(const float* __restrict__ x, float* __restrict__ pooled) {
    int plane = blockIdx.x;                       // n*256 + c
    const float* xp = x + (size_t)plane * (HW * HW);
    __shared__ float sm[HW * 97];                 // padded stride 97
    int t = threadIdx.x;
    #pragma unroll
    for (int k = 0; k < 9; ++k) {
        int idx = t + k * 256;                    // float4 index
        floatx4 v = ((const floatx4*)xp)[idx];
        int flat = idx * 4;
        int row = flat / HW;
        int col = flat - row * HW;
        float* d = &sm[row * 97 + col];
        d[0] = v.x; d[1] = v.y; d[2] = v.z; d[3] = v.w;
    }
    __syncthreads();
    float* pp = pooled + (size_t)plane * PTOT;
    if (t < HW) {
        float rs = 0.f;
        #pragma unroll 4
        for (int j = 0; j < HW; ++j) rs += sm[t * 97 + j];
        pp[t] = rs * (1.f / 96.f);
    } else if (t < 2 * HW) {
        int c = t - HW;
        float cs = 0.f;
        #pragma unroll 4
        for (int i = 0; i < HW; ++i) cs += sm[i * 97 + c];
        pp[HW + c] = cs * (1.f / 96.f);
    }
}

// ---------------------------------------------------------------------------
// Kernel B: ENTIRE mid pipeline, tile of 4 final positions.
// grid (48, 16) = 768 blocks x 256 thr = 3 blocks/CU = 12 waves/CU
// (vs round-0's 192 blocks = 0.75 waves/SIMD). Halo chain: final tile
// [p0,p0+4) -> yt at [p0-3,p0+7) (10 pos) -> y0 = conv at [p0-6,p0+10)
// (16 pos). Conv recompute 4x of a ~50 MFLOP conv -> negligible.
// 96 = 24*4 so tiles never straddle the h/w boundary (side block-uniform).
// All intermediates in LDS (~43 KB -> LDS allows 3 blocks/CU, = grid need).
// ---------------------------------------------------------------------------
__global__ __launch_bounds__(256) void megamid_kernel(
    const float* __restrict__ pooled,
    const float* __restrict__ w_c1, const float* __restrict__ b_c1,
    const float* __restrict__ i1_w1, const float* __restrict__ i1_b1,
    const float* __restrict__ i1_w2, const float* __restrict__ i1_b2,
    const float* __restrict__ bn_g, const float* __restrict__ bn_b,
    const float* __restrict__ bn_m, const float* __restrict__ bn_v,
    const float* __restrict__ h_w1, const float* __restrict__ h_b1,
    const float* __restrict__ h_w2, const float* __restrict__ h_b2,
    const float* __restrict__ w_h,  const float* __restrict__ b_h,
    const float* __restrict__ v_w1, const float* __restrict__ v_b1,
    const float* __restrict__ v_w2, const float* __restrict__ v_b2,
    const float* __restrict__ w_w,  const float* __restrict__ b_w,
    float* __restrict__ a_h, float* __restrict__ a_w)
{
    int p0 = blockIdx.x * 4;       // 0..188
    int n  = blockIdx.y;
    int t  = threadIdx.x;
    int side = (p0 >= HW) ? 1 : 0; // uniform per block
    int lo = side * HW;

    __shared__ float pt[256 * 16];   // pooled[c][j], j = r-(p0-6), 16 KB
    __shared__ float sw[64 * 65];    // transposed weight chunk, 16.6 KB
    __shared__ float y0t[16 * 64];   // conv out at [p0-6, p0+10)
    __shared__ float yt[10 * 64];    // mid1 out at [p0-3, p0+7)
    __shared__ float lt[10 * 16];
    __shared__ float lwgt[10 * 28];
    __shared__ float lt2[4 * 16];
    __shared__ float lwgt2[4 * 28];
    __shared__ float lz[4 * 64];

    // ---- stage pooled neighborhood: pt[c*16 + j], conflict-free writes ----
    {
        const float* pn = pooled + (size_t)n * C_IN * PTOT;
        #pragma unroll
        for (int i = 0; i < 16; ++i) {
            int flat = t + 256 * i;        // 4096 = 256*16
            int c = flat >> 4, j = flat & 15;
            int r = p0 - 6 + j;
            pt[flat] = (r >= 0 && r < PTOT) ? pn[c * PTOT + r] : 0.f;
        }
    }

    // ---- conv1x1 256->64 at 16 positions ----
    int o  = t & 63;
    int pg = t >> 6;                 // wave-uniform (wave w -> pg = w)
    int j0 = pg * 4;
    float acc[4] = {0.f, 0.f, 0.f, 0.f};
    for (int c0 = 0; c0 < C_IN; c0 += 64) {
        __syncthreads();             // first iter also guards pt
        #pragma unroll
        for (int i = 0; i < 16; ++i) {
            int flat = t + 256 * i;
            int oo = flat >> 6, cc = flat & 63;
            sw[oo * 65 + cc] = w_c1[oo * C_IN + c0 + cc];
        }
        __syncthreads();
        #pragma unroll 4
        for (int cc = 0; cc < 64; ++cc) {
            float wv = sw[o * 65 + cc];                      // (o+cc)%32: no conflict
            floatx4 pa = *(const floatx4*)&pt[(c0 + cc) * 16 + j0];  // wave-broadcast
            acc[0] += wv * pa.x; acc[1] += wv * pa.y;
            acc[2] += wv * pa.z; acc[3] += wv * pa.w;
        }
    }
    // involution1 zero-pads its INPUT (conv output incl bias) outside [0,192)
    {
        float bo = b_c1[o];
        #pragma unroll
        for (int e = 0; e < 4; ++e) {
            int j = j0 + e;
            int r = p0 - 6 + j;
            y0t[j * 64 + o] = (r >= 0 && r < PTOT) ? (acc[e] + bo) : 0.f;
        }
    }
    __syncthreads();

    // ---- mid1: lt = w1 . y0(center), 10 pos x 16 ----
    if (t < 160) {
        int q = t >> 4, i = t & 15;
        float a = i1_b1[i];
        const float* wr = i1_w1 + i * MIP;
        #pragma unroll 8
        for (int oo = 0; oo < MIP; ++oo) a += wr[oo] * y0t[(q + 3) * 64 + oo];
        lt[t] = a;
    }
    __syncthreads();
    // ---- mid1: lwgt (only taps ky*7+3 survive on the (192,1) map) ----
    for (int idx = t; idx < 280; idx += 256) {   // 10*28
        int q = idx / 28, m = idx - q * 28;
        int g = m / 7, ky = m - g * 7;
        int wq = g * 49 + ky * 7 + 3;
        float a = i1_b2[wq];
        const float* wr = i1_w2 + wq * 16;
        #pragma unroll
        for (int r = 0; r < 16; ++r) a += wr[r] * lt[q * 16 + r];
        lwgt[idx] = a;
    }
    __syncthreads();
    // ---- mid1: involution + BN + hswish -> yt, 10 pos x 64 ch ----
    for (int idx = t; idx < 640; idx += 256) {
        int q = idx >> 6, ch = idx & 63;
        int g = ch >> 4;
        float a = 0.f;
        #pragma unroll
        for (int ky = 0; ky < KK; ++ky)
            a += lwgt[q * 28 + g * 7 + ky] * y0t[(q + ky) * 64 + ch];
        float inv_std = rsqrtf(bn_v[ch] + 1e-5f);
        float v = (a - bn_m[ch]) * (bn_g[ch] * inv_std) + bn_b[ch];
        yt[idx] = v * fminf(fmaxf(v + 3.f, 0.f), 6.f) * (1.f / 6.f);
    }
    __syncthreads();

    // ---- mid2 (branch weights uniform per block) ----
    const float* ww1 = side ? v_w1 : h_w1;
    const float* bb1 = side ? v_b1 : h_b1;
    const float* ww2 = side ? v_w2 : h_w2;
    const float* bb2 = side ? v_b2 : h_b2;
    const float* wf  = side ? w_w  : w_h;
    const float* bf  = side ? b_w  : b_h;

    // lt2: 4 pos x 16 (center p0+pp is always inside the half)
    if (t < 64) {
        int pp = t >> 4, i = t & 15;
        float a = bb1[i];
        const float* wr = ww1 + i * MIP;
        #pragma unroll 8
        for (int oo = 0; oo < MIP; ++oo) a += wr[oo] * yt[(pp + 3) * 64 + oo];
        lt2[t] = a;
    }
    __syncthreads();
    // lwgt2: H side taps ky*7+3, W side taps 21+kx
    if (t < 112) {     // 4*28
        int pp = t / 28, m = t - pp * 28;
        int g = m / 7, kk = m - g * 7;
        int wq = side ? (g * 49 + 21 + kk) : (g * 49 + kk * 7 + 3);
        float a = bb2[wq];
        const float* wr = ww2 + wq * 16;
        #pragma unroll
        for (int r = 0; r < 16; ++r) a += wr[r] * lt2[pp * 16 + r];
        lwgt2[t] = a;
    }
    __syncthreads();
    // lz: involution over the half (zero outside [lo, lo+96))
    if (t < 256) {     // 4*64 = 256, one per thread
        int pp = t >> 6, ch = t & 63;
        int g = ch >> 4;
        float a = 0.f;
        #pragma unroll
        for (int k = 0; k < KK; ++k) {
            int pos = p0 + pp + k - 3;
            float v = (pos >= lo && pos < lo + HW) ? yt[(pp + k) * 64 + ch] : 0.f;
            a += lwgt2[pp * 28 + g * 7 + k] * v;
        }
        lz[t] = a;
    }
    __syncthreads();
    // ---- final conv 64->256 + sigmoid; thread t = co, float4 weight loads ----
    {
        int co = t;
        float accf[4];
        float bfv = bf[co];
        #pragma unroll
        for (int pp = 0; pp < 4; ++pp) accf[pp] = bfv;
        const floatx4* wr4 = (const floatx4*)(wf + co * MIP);
        #pragma unroll 4
        for (int c4 = 0; c4 < 16; ++c4) {
            floatx4 w4 = wr4[c4];
            int ch = c4 * 4;
            #pragma unroll
            for (int pp = 0; pp < 4; ++pp) {
                accf[pp] += w4.x * lz[pp * 64 + ch + 0];
                accf[pp] += w4.y * lz[pp * 64 + ch + 1];
                accf[pp] += w4.z * lz[pp * 64 + ch + 2];
                accf[pp] += w4.w * lz[pp * 64 + ch + 3];
            }
        }
        float* dst = side ? a_w : a_h;
        floatx4 r;
        r.x = 1.f / (1.f + __expf(-accf[0]));
        r.y = 1.f / (1.f + __expf(-accf[1]));
        r.z = 1.f / (1.f + __expf(-accf[2]));
        r.w = 1.f / (1.f + __expf(-accf[3]));
        *(floatx4*)&dst[((size_t)n * C_IN + co) * HW + (p0 - lo)] = r;
    }
}

// ---------------------------------------------------------------------------
// Kernel C: out = x * a_w[j] * a_h[i], per-plane, float4, NT stores
// (verified, unchanged)
// ---------------------------------------------------------------------------
__global__ void apply_kernel(const float* __restrict__ x,
                             const float* __restrict__ a_h, const float* __restrict__ a_w,
                             float* __restrict__ out) {
    int plane = blockIdx.x;   // n*256 + c
    const floatx4* xp = (const floatx4*)(x + (size_t)plane * (HW * HW));
    floatx4* op = (floatx4*)(out + (size_t)plane * (HW * HW));
    __shared__ float sah[HW];
    __shared__ float saw[HW];
    int t = threadIdx.x;
    if (t < HW) {
        sah[t] = a_h[(size_t)plane * HW + t];
        saw[t] = a_w[(size_t)plane * HW + t];
    }
    __syncthreads();
    #pragma unroll
    for (int k = 0; k < 9; ++k) {
        int idx = t + k * 256;          // float4 index, 2304 per plane
        floatx4 v = xp[idx];
        int row = idx / 24;
        int c4 = (idx - row * 24) * 4;
        float ah = sah[row];
        v.x *= ah * saw[c4 + 0];
        v.y *= ah * saw[c4 + 1];
        v.z *= ah * saw[c4 + 2];
        v.w *= ah * saw[c4 + 3];
        __builtin_nontemporal_store(v, &op[idx]);
    }
}

extern "C" void kernel_launch(void* const* d_in, const int* in_sizes, int n_in,
                              void* d_out, int out_size, void* d_ws, size_t ws_size,
                              hipStream_t stream) {
    const float* x      = (const float*)d_in[0];
    const float* w_c1   = (const float*)d_in[1];
    const float* b_c1   = (const float*)d_in[2];
    const float* i1_w1  = (const float*)d_in[3];
    const float* i1_b1  = (const float*)d_in[4];
    const float* i1_w2  = (const float*)d_in[5];
    const float* i1_b2  = (const float*)d_in[6];
    const float* bn_g   = (const float*)d_in[7];
    const float* bn_b   = (const float*)d_in[8];
    const float* bn_m   = (const float*)d_in[9];
    const float* bn_v   = (const float*)d_in[10];
    const float* ih_w1  = (const float*)d_in[11];
    const float* ih_b1  = (const float*)d_in[12];
    const float* ih_w2  = (const float*)d_in[13];
    const float* ih_b2  = (const float*)d_in[14];
    const float* w_h    = (const float*)d_in[15];
    const float* b_h    = (const float*)d_in[16];
    const float* iw_w1  = (const float*)d_in[17];
    const float* iw_b1  = (const float*)d_in[18];
    const float* iw_w2  = (const float*)d_in[19];
    const float* iw_b2  = (const float*)d_in[20];
    const float* w_w    = (const float*)d_in[21];
    const float* b_w    = (const float*)d_in[22];
    float* out = (float*)d_out;

    // Workspace: EXACTLY the verified 1,572,864-float footprint, no aliasing.
    float* ws = (float*)d_ws;
    float* pooled = ws;                       // 786432 floats
    float* a_h    = pooled + 786432;          // 393216
    float* a_w    = a_h + 393216;             // 393216

    pool_kernel<<<dim3(N_B * C_IN), dim3(256), 0, stream>>>(x, pooled);
    megamid_kernel<<<dim3(48, N_B), dim3(256), 0, stream>>>(
        pooled, w_c1, b_c1, i1_w1, i1_b1, i1_w2, i1_b2,
        bn_g, bn_b, bn_m, bn_v,
        ih_w1, ih_b1, ih_w2, ih_b2, w_h, b_h,
        iw_w1, iw_b1, iw_w2, iw_b2, w_w, b_w, a_h, a_w);
    apply_kernel<<<dim3(N_B * C_IN), dim3(256), 0, stream>>>(x, a_h, a_w, out);
}